// Round 9
// baseline (194.893 us; speedup 1.0000x reference)
//
#include <hip/hip_runtime.h>
#include <hip/hip_bf16.h>

#define FEAT 256
#define HEADS 8
#define HD 32
#define POSN 128
#define NEGN 128
#define HWN 16384
#define BN 8
#define NSLOT 512
#define S_TOT 256
#define LN_EPS 1e-5f
#define NBKT 4096
#define NKEY (HWN*BN)          /* 131072 (row,batch) keys == feature row index */
#define AFF_OFF (NSLOT*FEAT)   /* 131072 floats: new_slots first, then affinities */

typedef float f32x4 __attribute__((ext_vector_type(4)));

__device__ __forceinline__ unsigned short bf16r(float x) {
    unsigned int u = __float_as_uint(x);
    u += 0x7FFFu + ((u >> 16) & 1u);       // round to nearest even
    return (unsigned short)(u >> 16);
}
__device__ __forceinline__ float bf16f(unsigned short h) {
    return __uint_as_float((unsigned int)h << 16);
}

// ---------------- K1: exact feat_idx sampling + folded qkw + key histogram ---
__global__ __launch_bounds__(256) void k_sample_qkw(const float* __restrict__ curio,
                                                    const int* __restrict__ mme_p,
                                                    const float* __restrict__ slots,
                                                    const float* __restrict__ ipw,
                                                    const float* __restrict__ ipb,
                                                    const int* __restrict__ batch_idx,
                                                    int* __restrict__ fi_t,
                                                    float* __restrict__ qkw,
                                                    float* __restrict__ qkb,
                                                    unsigned int* __restrict__ counts)
{
    __shared__ unsigned int hist[NBKT];   // 16KB
    __shared__ uint16_t offs[NBKT];       // 8KB
    __shared__ uint16_t sidx[HWN];        // 32KB
    __shared__ unsigned int ssum[256];    // 1KB
    __shared__ float srow[FEAT];          // 1KB
    __shared__ float qrow[FEAT];          // 1KB
    int slot = blockIdx.x, t = threadIdx.x;
    const float* cm = curio + (size_t)slot * HWN;
    const f32x4* cm4 = (const f32x4*)cm;

    for (int i = t; i < NBKT; i += 256) hist[i] = 0;
    __syncthreads();

    // pass 1: vectorized stream + histogram; cache bucket ids in registers
    unsigned int bkA[16], bkB[16];
#pragma unroll
    for (int j = 0; j < 16; j++) {
        f32x4 v = cm4[j * 256 + t];
        int b0 = (int)(v[0] * 4096.0f); b0 = b0 < 0 ? 0 : (b0 > NBKT-1 ? NBKT-1 : b0);
        int b1 = (int)(v[1] * 4096.0f); b1 = b1 < 0 ? 0 : (b1 > NBKT-1 ? NBKT-1 : b1);
        int b2 = (int)(v[2] * 4096.0f); b2 = b2 < 0 ? 0 : (b2 > NBKT-1 ? NBKT-1 : b2);
        int b3 = (int)(v[3] * 4096.0f); b3 = b3 < 0 ? 0 : (b3 > NBKT-1 ? NBKT-1 : b3);
        bkA[j] = (unsigned int)b0 | ((unsigned int)b1 << 16);
        bkB[j] = (unsigned int)b2 | ((unsigned int)b3 << 16);
        atomicAdd(&hist[b0], 1u); atomicAdd(&hist[b1], 1u);
        atomicAdd(&hist[b2], 1u); atomicAdd(&hist[b3], 1u);
    }
    __syncthreads();

    // descending-order exclusive prefix: offs[b] = sum_{b'>b} hist[b']
    unsigned int lsum = 0;
    int base = t * 16;
    for (int j = 0; j < 16; j++) lsum += hist[NBKT-1 - (base + j)];
    ssum[t] = lsum; __syncthreads();
    for (int off = 1; off < 256; off <<= 1) {
        unsigned int v = (t >= off) ? ssum[t - off] : 0u;
        __syncthreads();
        ssum[t] += v;
        __syncthreads();
    }
    unsigned int run = ssum[t] - lsum;
    for (int j = 0; j < 16; j++) {
        int b = NBKT-1 - (base + j);
        offs[b] = (uint16_t)run;
        run += hist[b];
    }
    __syncthreads();
    for (int i = t; i < NBKT; i += 256) hist[i] = 0;
    __syncthreads();

    // pass 2: scatter from register-cached buckets (no curio re-read)
#pragma unroll
    for (int j = 0; j < 16; j++) {
        int idx0 = (j * 256 + t) * 4;
        int b0 = (int)(bkA[j] & 0xFFFFu), b1 = (int)(bkA[j] >> 16);
        int b2 = (int)(bkB[j] & 0xFFFFu), b3 = (int)(bkB[j] >> 16);
        unsigned int p0 = (unsigned int)offs[b0] + atomicAdd(&hist[b0], 1u);
        sidx[p0] = (uint16_t)(idx0 + 0);
        unsigned int p1 = (unsigned int)offs[b1] + atomicAdd(&hist[b1], 1u);
        sidx[p1] = (uint16_t)(idx0 + 1);
        unsigned int p2 = (unsigned int)offs[b2] + atomicAdd(&hist[b2], 1u);
        sidx[p2] = (uint16_t)(idx0 + 2);
        unsigned int p3 = (unsigned int)offs[b3] + atomicAdd(&hist[b3], 1u);
        sidx[p3] = (uint16_t)(idx0 + 3);
    }
    __syncthreads();

    // exact rank selection (argsort of -v, stable: value desc, idx asc)
    int mme = mme_p[0];
    int stride = (HWN - POSN - mme) / NEGN;          // 127 for mme=0
    int r = (t < POSN) ? t : (POSN + stride * (t - POSN));
    int lo = 0, hi = NBKT - 1;
    while (lo < hi) { int mid = (lo + hi) >> 1; if ((int)offs[mid] <= r) hi = mid; else lo = mid + 1; }
    int bkt = lo;
    int start = (int)offs[bkt];
    int cnt   = (int)hist[bkt];
    int rr = r - start;
    int besti = sidx[start + (rr < cnt ? rr : 0)];
    for (int j = 0; j < cnt; j++) {
        int ij = sidx[start + j];
        float vj = cm[ij];
        int rank = 0;
        for (int j2 = 0; j2 < cnt; j2++) {
            int i2 = sidx[start + j2];
            float v2 = cm[i2];
            if (v2 > vj || (v2 == vj && i2 < ij)) rank++;
        }
        if (rank == rr) { besti = ij; break; }
    }
    fi_t[slot * S_TOT + t] = besti;   // fi_t[n][s]

    // key histogram for the global row-sort
    {
        int b = batch_idx[slot];
        atomicAdd(&counts[besti * BN + b], 1u);
    }

    // ---- folded qkw for this slot ----
    __syncthreads();
    srow[t] = slots[slot * FEAT + t];
    __syncthreads();
    {
        const float* qwrow = ipw + (size_t)t * FEAT;
        float acc = 0.f;
#pragma unroll 8
        for (int f = 0; f < FEAT; f++) acc += srow[f] * qwrow[f];
        const float scaling = 0.17677669529663687f;     // 32^-0.5
        qrow[t] = (acc + ipb[t]) * scaling;
    }
    __syncthreads();
    if (t < HEADS) {
        float s = 0.f;
        for (int d = 0; d < HD; d++) s += qrow[t*HD + d] * ipb[FEAT + t*HD + d];
        qkb[slot * HEADS + t] = s;
    }
    const float* kw = ipw + FEAT * FEAT;
    for (int e = t; e < HEADS * FEAT; e += 256) {
        int h = e >> 8, f = e & 255;
        float s = 0.f;
#pragma unroll
        for (int d = 0; d < HD; d++) s += qrow[h*HD + d] * kw[(h*HD + d) * FEAT + f];
        qkw[(size_t)slot * (HEADS*FEAT) + e] = s;
    }
}

// ---------------- scan A: per-block exclusive scan of counts -----------------
__global__ __launch_bounds__(256) void k_scanA(const unsigned int* __restrict__ counts,
                                               unsigned int* __restrict__ localpre,
                                               unsigned int* __restrict__ bsum)
{
    __shared__ unsigned int sc[256];
    int t = threadIdx.x;
    int key = blockIdx.x * 256 + t;
    unsigned int c = counts[key];
    sc[t] = c; __syncthreads();
    for (int off = 1; off < 256; off <<= 1) {
        unsigned int v = (t >= off) ? sc[t - off] : 0u;
        __syncthreads();
        sc[t] += v;
        __syncthreads();
    }
    localpre[key] = sc[t] - c;
    if (t == 255) bsum[blockIdx.x] = sc[255];
}

// ---------------- scan B: exclusive scan of 512 block sums -------------------
__global__ __launch_bounds__(512) void k_scanB(const unsigned int* __restrict__ bsum,
                                               unsigned int* __restrict__ bpre)
{
    __shared__ unsigned int sc[512];
    int t = threadIdx.x;
    unsigned int c = bsum[t];
    sc[t] = c; __syncthreads();
    for (int off = 1; off < 512; off <<= 1) {
        unsigned int v = (t >= off) ? sc[t - off] : 0u;
        __syncthreads();
        sc[t] += v;
        __syncthreads();
    }
    bpre[t] = sc[t] - c;
}

// ---------------- scatter: build row-sorted ref list -------------------------
__global__ __launch_bounds__(256) void k_scatter(const int* __restrict__ fi_t,
                                                 const int* __restrict__ batch_idx,
                                                 const unsigned int* __restrict__ localpre,
                                                 const unsigned int* __restrict__ bpre,
                                                 unsigned int* __restrict__ counts,   // consumed as cursor
                                                 unsigned int* __restrict__ skey,
                                                 unsigned int* __restrict__ spay)
{
    int slot = blockIdx.x, t = threadIdx.x;
    int besti = fi_t[slot * S_TOT + t];
    int b = batch_idx[slot];
    unsigned int key = (unsigned int)(besti * BN + b);
    unsigned int old = atomicSub(&counts[key], 1u);
    unsigned int pos = localpre[key] + bpre[key >> 8] + old - 1u;
    skey[pos] = key;
    spay[pos] = ((unsigned int)slot << 8) | (unsigned int)t;
}

// ---------------- K2: row-sorted gather affinity + POS stash -----------------
// 2048 blocks x 256 thr; each wave processes 16 consecutive refs of the
// row-sorted list -> ascending, nearly-dense addresses (DRAM row-buffer
// friendly; duplicate rows hit L1/L2). Depth-3 row prefetch, depth-1 qkw
// prefetch, fully unrolled (static reg indexing).
__global__ __launch_bounds__(256) void k_aff_sorted(const float* __restrict__ features,
                                                    const float* __restrict__ pos_enc,
                                                    const float* __restrict__ qkw,
                                                    const float* __restrict__ qkb,
                                                    const unsigned int* __restrict__ skey,
                                                    const unsigned int* __restrict__ spay,
                                                    unsigned short* __restrict__ stash,
                                                    float* __restrict__ aff_out)
{
    __shared__ unsigned int kys[64], pls[64];
    int t = threadIdx.x, lane = t & 63, w = t >> 6;
    int base = blockIdx.x * 64;
    if (t < 64) { kys[t] = skey[base + t]; pls[t] = spay[base + t]; }
    __syncthreads();
    int b0 = lane & 1, b1 = (lane >> 1) & 1, b2 = (lane >> 2) & 1;
    int r0 = w * 16;

    f32x4 fb[4], gb[4];
    f32x4 qb[2][8];
    float qkbv[2];

    // prologue: rows j=0..2, qkw j=0
    {
        size_t a0 = (size_t)kys[r0+0] * FEAT + 4*lane;
        fb[0] = *(const f32x4*)(features + a0); gb[0] = *(const f32x4*)(pos_enc + a0);
        size_t a1 = (size_t)kys[r0+1] * FEAT + 4*lane;
        fb[1] = *(const f32x4*)(features + a1); gb[1] = *(const f32x4*)(pos_enc + a1);
        size_t a2 = (size_t)kys[r0+2] * FEAT + 4*lane;
        fb[2] = *(const f32x4*)(features + a2); gb[2] = *(const f32x4*)(pos_enc + a2);
        int n0 = (int)(pls[r0] >> 8);
        const float* qk = qkw + (size_t)n0 * (HEADS*FEAT) + 4*lane;
#pragma unroll
        for (int h = 0; h < 8; h++) qb[0][h] = *(const f32x4*)(qk + h*FEAT);
        qkbv[0] = qkb[n0 * HEADS + (lane & 7)];
    }

#pragma unroll
    for (int j = 0; j < 16; j++) {
        if (j + 3 < 16) {
            size_t a = (size_t)kys[r0+j+3] * FEAT + 4*lane;
            fb[(j+3)&3] = *(const f32x4*)(features + a);
            gb[(j+3)&3] = *(const f32x4*)(pos_enc + a);
        }
        if (j + 1 < 16) {
            int nn = (int)(pls[r0+j+1] >> 8);
            const float* qk = qkw + (size_t)nn * (HEADS*FEAT) + 4*lane;
#pragma unroll
            for (int h = 0; h < 8; h++) qb[(j+1)&1][h] = *(const f32x4*)(qk + h*FEAT);
            qkbv[(j+1)&1] = qkb[nn * HEADS + (lane & 7)];
        }
        unsigned int pl = pls[r0+j];
        int n = (int)(pl >> 8), s = (int)(pl & 255u);
        f32x4 cf = fb[j&3];
        f32x4 x = cf + gb[j&3];
        float p0 = x[0]*qb[j&1][0][0] + x[1]*qb[j&1][0][1] + x[2]*qb[j&1][0][2] + x[3]*qb[j&1][0][3];
        float p1 = x[0]*qb[j&1][1][0] + x[1]*qb[j&1][1][1] + x[2]*qb[j&1][1][2] + x[3]*qb[j&1][1][3];
        float p2 = x[0]*qb[j&1][2][0] + x[1]*qb[j&1][2][1] + x[2]*qb[j&1][2][2] + x[3]*qb[j&1][2][3];
        float p3 = x[0]*qb[j&1][3][0] + x[1]*qb[j&1][3][1] + x[2]*qb[j&1][3][2] + x[3]*qb[j&1][3][3];
        float p4 = x[0]*qb[j&1][4][0] + x[1]*qb[j&1][4][1] + x[2]*qb[j&1][4][2] + x[3]*qb[j&1][4][3];
        float p5 = x[0]*qb[j&1][5][0] + x[1]*qb[j&1][5][1] + x[2]*qb[j&1][5][2] + x[3]*qb[j&1][5][3];
        float p6 = x[0]*qb[j&1][6][0] + x[1]*qb[j&1][6][1] + x[2]*qb[j&1][6][2] + x[3]*qb[j&1][6][3];
        float p7 = x[0]*qb[j&1][7][0] + x[1]*qb[j&1][7][1] + x[2]*qb[j&1][7][2] + x[3]*qb[j&1][7][3];
        float s0 = b0 ? p0 : p1, s1 = b0 ? p2 : p3, s2 = b0 ? p4 : p5, s3 = b0 ? p6 : p7;
        float a0 = (b0 ? p1 : p0) + __shfl_xor(s0, 1);
        float a1 = (b0 ? p3 : p2) + __shfl_xor(s1, 1);
        float a2 = (b0 ? p5 : p4) + __shfl_xor(s2, 1);
        float a3 = (b0 ? p7 : p6) + __shfl_xor(s3, 1);
        float u0 = b1 ? a0 : a1, u1 = b1 ? a2 : a3;
        float c0 = (b1 ? a1 : a0) + __shfl_xor(u0, 2);
        float c1 = (b1 ? a3 : a2) + __shfl_xor(u1, 2);
        float u2 = b2 ? c0 : c1;
        float d = (b2 ? c1 : c0) + __shfl_xor(u2, 4);
        d += __shfl_xor(d, 8);
        d += __shfl_xor(d, 16);
        d += __shfl_xor(d, 32);
        d += qkbv[j&1];
        if (lane < 8)
            aff_out[(size_t)s * (NSLOT*HEADS) + n*HEADS + lane] = d;
        if (s < POSN) {     // stash POS feature row as bf16 (uniform branch)
            ushort4 s4;
            s4.x = bf16r(cf[0]); s4.y = bf16r(cf[1]);
            s4.z = bf16r(cf[2]); s4.w = bf16r(cf[3]);
            *(ushort4*)(stash + ((size_t)n * POSN + s) * FEAT + 4*lane) = s4;
        }
    }
}

// ---------------- K3: softmax + weighted-feat + Vproj + Oproj + LN -----------
__global__ __launch_bounds__(512) void k_out(const unsigned short* __restrict__ stash,
                                             const float* __restrict__ slots,
                                             const float* __restrict__ ipw,
                                             const float* __restrict__ ipb,
                                             const float* __restrict__ out_w,
                                             const float* __restrict__ out_b,
                                             const float* __restrict__ ln_g,
                                             const float* __restrict__ ln_b,
                                             const float* __restrict__ aff,
                                             float* __restrict__ out)
{
    __shared__ __align__(16) float affP[POSN][8];      // 4KB: aff then attn
    __shared__ f32x4 wfp[4][HEADS][64];                // 32KB per-wave partials
    __shared__ f32x4 wf4[HEADS][64];                   // 8KB combined
    __shared__ float aoh[512];                         // 2KB
    __shared__ __align__(16) float ao_l[FEAT];         // 1KB
    __shared__ float xgh[512];                         // 2KB
    __shared__ float r1[4], r2[4];

    int n = blockIdx.x, t = threadIdx.x, lane = t & 63, w = t >> 6;
    for (int e = t; e < POSN * HEADS; e += 512) {
        int p = e >> 3, h = e & 7;
        affP[p][h] = aff[(size_t)p * (NSLOT*HEADS) + n*HEADS + h];
    }

    // stream this slot's 16 stash rows per wave (latency overlaps softmax)
    f32x4 cache[16];
#pragma unroll
    for (int i = 0; i < 16; i++) {
        ushort4 s4 = *(const ushort4*)(stash + ((size_t)n * POSN + (w + 8*i)) * FEAT + 4*lane);
        f32x4 v;
        v[0] = bf16f(s4.x); v[1] = bf16f(s4.y); v[2] = bf16f(s4.z); v[3] = bf16f(s4.w);
        cache[i] = v;
    }
    __syncthreads();

    if (t < 256) {
        int h = t >> 5, l = t & 31;
        float v0 = affP[l][h], v1 = affP[l+32][h], v2 = affP[l+64][h], v3 = affP[l+96][h];
        float m = fmaxf(fmaxf(v0, v1), fmaxf(v2, v3));
        for (int off = 16; off > 0; off >>= 1) m = fmaxf(m, __shfl_xor(m, off, 32));
        float e0 = expf(v0 - m), e1 = expf(v1 - m), e2 = expf(v2 - m), e3 = expf(v3 - m);
        float s = e0 + e1 + e2 + e3;
        for (int off = 16; off > 0; off >>= 1) s += __shfl_xor(s, off, 32);
        float inv = 1.0f / s;
        affP[l][h] = e0*inv; affP[l+32][h] = e1*inv; affP[l+64][h] = e2*inv; affP[l+96][h] = e3*inv;
    }
    __syncthreads();

    {
        f32x4 acc[8];
#pragma unroll
        for (int h = 0; h < 8; h++) acc[h] = (f32x4){0.f,0.f,0.f,0.f};
#pragma unroll
        for (int i = 0; i < 16; i++) {
            int p = w + 8*i;
            const f32x4* ap = (const f32x4*)&affP[p][0];
            f32x4 a03 = ap[0], a47 = ap[1];
            acc[0] += cache[i] * a03[0];
            acc[1] += cache[i] * a03[1];
            acc[2] += cache[i] * a03[2];
            acc[3] += cache[i] * a03[3];
            acc[4] += cache[i] * a47[0];
            acc[5] += cache[i] * a47[1];
            acc[6] += cache[i] * a47[2];
            acc[7] += cache[i] * a47[3];
        }
        if (w < 4) {
#pragma unroll
            for (int h = 0; h < 8; h++) wfp[w][h][lane] = acc[h];
        }
        __syncthreads();
        if (w >= 4) {
#pragma unroll
            for (int h = 0; h < 8; h++) wfp[w-4][h][lane] += acc[h];
        }
        __syncthreads();
    }
    {
        int h = t >> 6, q2 = t & 63;
        f32x4 s = wfp[0][h][q2] + wfp[1][h][q2] + wfp[2][h][q2] + wfp[3][h][q2];
        wf4[h][q2] = s;
    }
    __syncthreads();

    {
        int g = t & 255, half = t >> 8;
        const float* vwrow = ipw + (size_t)(2*FEAT + g) * FEAT + half*128;
        const f32x4* wfv = &wf4[g >> 5][half*32];
        float s = 0.f;
#pragma unroll 8
        for (int f4i = 0; f4i < 32; f4i++) {
            f32x4 wv = *(const f32x4*)(vwrow + 4*f4i);
            f32x4 y = wfv[f4i];
            s += wv[0]*y[0] + wv[1]*y[1] + wv[2]*y[2] + wv[3]*y[3];
        }
        aoh[t] = s;
    }
    __syncthreads();
    if (t < 256) ao_l[t] = aoh[t] + aoh[t + 256] + ipb[2*FEAT + t];
    __syncthreads();

    {
        int g = t & 255, half = t >> 8;
        const float* owrow = out_w + (size_t)g * FEAT + half*128;
        const f32x4* av = (const f32x4*)&ao_l[half*128];
        float s = 0.f;
#pragma unroll 8
        for (int f4i = 0; f4i < 32; f4i++) {
            f32x4 wv = *(const f32x4*)(owrow + 4*f4i);
            f32x4 y = av[f4i];
            s += wv[0]*y[0] + wv[1]*y[1] + wv[2]*y[2] + wv[3]*y[3];
        }
        xgh[t] = s;
    }
    __syncthreads();

    float xg = 0.f;
    if (t < 256) {
        xg = xgh[t] + xgh[t + 256] + out_b[t] + slots[n * FEAT + t];
        float s1 = xg, s2 = xg * xg;
        for (int off = 32; off > 0; off >>= 1) {
            s1 += __shfl_xor(s1, off);
            s2 += __shfl_xor(s2, off);
        }
        if ((t & 63) == 0) { r1[t >> 6] = s1; r2[t >> 6] = s2; }
    }
    __syncthreads();
    if (t < 256) {
        float sum1 = r1[0] + r1[1] + r1[2] + r1[3];
        float sum2 = r2[0] + r2[1] + r2[2] + r2[3];
        float mu  = sum1 * (1.0f / FEAT);
        float var = sum2 * (1.0f / FEAT) - mu * mu;
        float nrm = (xg - mu) * rsqrtf(var + LN_EPS);
        out[n * FEAT + t] = nrm * ln_g[t] + ln_b[t];
    }
}

extern "C" void kernel_launch(void* const* d_in, const int* in_sizes, int n_in,
                              void* d_out, int out_size, void* d_ws, size_t ws_size,
                              hipStream_t stream)
{
    (void)in_sizes; (void)n_in; (void)out_size; (void)ws_size;
    const float* slots    = (const float*)d_in[0];
    const float* features = (const float*)d_in[1];
    const float* pos_enc  = (const float*)d_in[2];
    const float* curio    = (const float*)d_in[3];
    const int*   batch_idx= (const int*)d_in[4];
    const float* ipw      = (const float*)d_in[5];
    const float* ipb      = (const float*)d_in[6];
    const float* out_w    = (const float*)d_in[7];
    const float* out_b    = (const float*)d_in[8];
    const float* ln_g     = (const float*)d_in[9];
    const float* ln_b     = (const float*)d_in[10];
    const int*   mme      = (const int*)d_in[11];
    float* out = (float*)d_out;

    char* ws = (char*)d_ws;
    const size_t OFF_QKW   = 512u << 10;                  // fi_t: [0,512K)
    const size_t OFF_QKB   = OFF_QKW  + (4u << 20);       // qkw 4MB
    const size_t OFF_CNT   = OFF_QKB  + (64u << 10);      // qkb 16K (pad 64K)
    const size_t OFF_LPRE  = OFF_CNT  + (512u << 10);     // counts 512K
    const size_t OFF_BSUM  = OFF_LPRE + (512u << 10);     // localpre 512K
    const size_t OFF_BPRE  = OFF_BSUM + (4u << 10);       // bsum 2K (pad 4K)
    const size_t OFF_SKEY  = OFF_BPRE + (4u << 10);       // bpre 2K (pad 4K)
    const size_t OFF_SPAY  = OFF_SKEY + (512u << 10);     // skey 512K
    const size_t OFF_STASH = OFF_SPAY + (512u << 10);     // spay 512K

    int*   fi_t = (int*)ws;
    float* qkw  = (float*)(ws + OFF_QKW);
    float* qkb  = (float*)(ws + OFF_QKB);
    unsigned int* counts   = (unsigned int*)(ws + OFF_CNT);
    unsigned int* localpre = (unsigned int*)(ws + OFF_LPRE);
    unsigned int* bsum     = (unsigned int*)(ws + OFF_BSUM);
    unsigned int* bpre     = (unsigned int*)(ws + OFF_BPRE);
    unsigned int* skey     = (unsigned int*)(ws + OFF_SKEY);
    unsigned int* spay     = (unsigned int*)(ws + OFF_SPAY);
    unsigned short* stash  = (unsigned short*)(ws + OFF_STASH);  // 16.78MB
    float* aff  = out + AFF_OFF;

    hipMemsetAsync(counts, 0, (size_t)NKEY * 4, stream);

    hipLaunchKernelGGL(k_sample_qkw, dim3(NSLOT), dim3(256), 0, stream,
                       curio, mme, slots, ipw, ipb, batch_idx, fi_t, qkw, qkb, counts);
    hipLaunchKernelGGL(k_scanA, dim3(NKEY/256), dim3(256), 0, stream, counts, localpre, bsum);
    hipLaunchKernelGGL(k_scanB, dim3(1), dim3(512), 0, stream, bsum, bpre);
    hipLaunchKernelGGL(k_scatter, dim3(NSLOT), dim3(256), 0, stream,
                       fi_t, batch_idx, localpre, bpre, counts, skey, spay);
    hipLaunchKernelGGL(k_aff_sorted, dim3(NKEY/64), dim3(256), 0, stream,
                       features, pos_enc, qkw, qkb, skey, spay, stash, aff);
    hipLaunchKernelGGL(k_out, dim3(NSLOT), dim3(512), 0, stream,
                       stash, slots, ipw, ipb, out_w, out_b, ln_g, ln_b, aff, out);
}

// Round 10
// 190.125 us; speedup vs baseline: 1.0251x; 1.0251x over previous
//
#include <hip/hip_runtime.h>
#include <hip/hip_bf16.h>

#define FEAT 256
#define HEADS 8
#define HD 32
#define POSN 128
#define NEGN 128
#define HWN 16384
#define BN 8
#define NSLOT 512
#define S_TOT 256
#define LN_EPS 1e-5f
#define NBKT 4096
#define AFF_OFF (NSLOT*FEAT)   /* 131072 floats: new_slots first, then affinities */

typedef float f32x4 __attribute__((ext_vector_type(4)));

__device__ __forceinline__ unsigned short bf16r(float x) {
    unsigned int u = __float_as_uint(x);
    u += 0x7FFFu + ((u >> 16) & 1u);       // round to nearest even
    return (unsigned short)(u >> 16);
}
__device__ __forceinline__ float bf16f(unsigned short h) {
    return __uint_as_float((unsigned int)h << 16);
}

// ---------------- K1: exact feat_idx sampling + folded qkw -------------------
__global__ __launch_bounds__(256) void k_sample_qkw(const float* __restrict__ curio,
                                                    const int* __restrict__ mme_p,
                                                    const float* __restrict__ slots,
                                                    const float* __restrict__ ipw,
                                                    const float* __restrict__ ipb,
                                                    int* __restrict__ fi_t,
                                                    float* __restrict__ qkw,
                                                    float* __restrict__ qkb)
{
    __shared__ unsigned int hist[NBKT];   // 16KB
    __shared__ uint16_t offs[NBKT];       // 8KB
    __shared__ uint16_t sidx[HWN];        // 32KB
    __shared__ unsigned int ssum[256];    // 1KB
    __shared__ float srow[FEAT];          // 1KB
    __shared__ float qrow[FEAT];          // 1KB
    int slot = blockIdx.x, t = threadIdx.x;
    const float* cm = curio + (size_t)slot * HWN;
    const f32x4* cm4 = (const f32x4*)cm;

    for (int i = t; i < NBKT; i += 256) hist[i] = 0;
    __syncthreads();

    // pass 1: vectorized stream + histogram; cache bucket ids in registers
    unsigned int bkA[16], bkB[16];
#pragma unroll
    for (int j = 0; j < 16; j++) {
        f32x4 v = cm4[j * 256 + t];
        int b0 = (int)(v[0] * 4096.0f); b0 = b0 < 0 ? 0 : (b0 > NBKT-1 ? NBKT-1 : b0);
        int b1 = (int)(v[1] * 4096.0f); b1 = b1 < 0 ? 0 : (b1 > NBKT-1 ? NBKT-1 : b1);
        int b2 = (int)(v[2] * 4096.0f); b2 = b2 < 0 ? 0 : (b2 > NBKT-1 ? NBKT-1 : b2);
        int b3 = (int)(v[3] * 4096.0f); b3 = b3 < 0 ? 0 : (b3 > NBKT-1 ? NBKT-1 : b3);
        bkA[j] = (unsigned int)b0 | ((unsigned int)b1 << 16);
        bkB[j] = (unsigned int)b2 | ((unsigned int)b3 << 16);
        atomicAdd(&hist[b0], 1u); atomicAdd(&hist[b1], 1u);
        atomicAdd(&hist[b2], 1u); atomicAdd(&hist[b3], 1u);
    }
    __syncthreads();

    // descending-order exclusive prefix: offs[b] = sum_{b'>b} hist[b']
    unsigned int lsum = 0;
    int base = t * 16;
    for (int j = 0; j < 16; j++) lsum += hist[NBKT-1 - (base + j)];
    ssum[t] = lsum; __syncthreads();
    for (int off = 1; off < 256; off <<= 1) {
        unsigned int v = (t >= off) ? ssum[t - off] : 0u;
        __syncthreads();
        ssum[t] += v;
        __syncthreads();
    }
    unsigned int run = ssum[t] - lsum;
    for (int j = 0; j < 16; j++) {
        int b = NBKT-1 - (base + j);
        offs[b] = (uint16_t)run;
        run += hist[b];
    }
    __syncthreads();
    for (int i = t; i < NBKT; i += 256) hist[i] = 0;
    __syncthreads();

    // pass 2: scatter from register-cached buckets (no curio re-read)
#pragma unroll
    for (int j = 0; j < 16; j++) {
        int idx0 = (j * 256 + t) * 4;
        int b0 = (int)(bkA[j] & 0xFFFFu), b1 = (int)(bkA[j] >> 16);
        int b2 = (int)(bkB[j] & 0xFFFFu), b3 = (int)(bkB[j] >> 16);
        unsigned int p0 = (unsigned int)offs[b0] + atomicAdd(&hist[b0], 1u);
        sidx[p0] = (uint16_t)(idx0 + 0);
        unsigned int p1 = (unsigned int)offs[b1] + atomicAdd(&hist[b1], 1u);
        sidx[p1] = (uint16_t)(idx0 + 1);
        unsigned int p2 = (unsigned int)offs[b2] + atomicAdd(&hist[b2], 1u);
        sidx[p2] = (uint16_t)(idx0 + 2);
        unsigned int p3 = (unsigned int)offs[b3] + atomicAdd(&hist[b3], 1u);
        sidx[p3] = (uint16_t)(idx0 + 3);
    }
    __syncthreads();

    // exact rank selection (argsort of -v, stable: value desc, idx asc)
    int mme = mme_p[0];
    int stride = (HWN - POSN - mme) / NEGN;          // 127 for mme=0
    int r = (t < POSN) ? t : (POSN + stride * (t - POSN));
    int lo = 0, hi = NBKT - 1;
    while (lo < hi) { int mid = (lo + hi) >> 1; if ((int)offs[mid] <= r) hi = mid; else lo = mid + 1; }
    int bkt = lo;
    int start = (int)offs[bkt];
    int cnt   = (int)hist[bkt];
    int rr = r - start;
    int besti = sidx[start + (rr < cnt ? rr : 0)];
    for (int j = 0; j < cnt; j++) {
        int ij = sidx[start + j];
        float vj = cm[ij];
        int rank = 0;
        for (int j2 = 0; j2 < cnt; j2++) {
            int i2 = sidx[start + j2];
            float v2 = cm[i2];
            if (v2 > vj || (v2 == vj && i2 < ij)) rank++;
        }
        if (rank == rr) { besti = ij; break; }
    }
    fi_t[slot * S_TOT + t] = besti;   // fi_t[n][s]

    // ---- folded qkw for this slot ----
    __syncthreads();
    srow[t] = slots[slot * FEAT + t];
    __syncthreads();
    {
        const float* qwrow = ipw + (size_t)t * FEAT;
        float acc = 0.f;
#pragma unroll 8
        for (int f = 0; f < FEAT; f++) acc += srow[f] * qwrow[f];
        const float scaling = 0.17677669529663687f;     // 32^-0.5
        qrow[t] = (acc + ipb[t]) * scaling;
    }
    __syncthreads();
    if (t < HEADS) {
        float s = 0.f;
        for (int d = 0; d < HD; d++) s += qrow[t*HD + d] * ipb[FEAT + t*HD + d];
        qkb[slot * HEADS + t] = s;
    }
    const float* kw = ipw + FEAT * FEAT;
    for (int e = t; e < HEADS * FEAT; e += 256) {
        int h = e >> 8, f = e & 255;
        float s = 0.f;
#pragma unroll
        for (int d = 0; d < HD; d++) s += qrow[h*HD + d] * kw[(h*HD + d) * FEAT + f];
        qkw[(size_t)slot * (HEADS*FEAT) + e] = s;
    }
}

// ---------------- K2: fully fused attention, 256 thr / slot ------------------
// 4 waves x 64 rows each. Phase B: POS gather (rolling depth-2) + affinities,
// features cached bf16-packed in regs. Softmax. Phase C: NEG gather rolling,
// INTERLEAVED per-iteration with the weighted-sum VALU work so NEG HBM latency
// hides under epilogue compute. Then V-proj, out-proj, residual+LN. ~30KB LDS.
__global__ __launch_bounds__(256, 2) void k_attn(const float* __restrict__ features,
                                                 const float* __restrict__ pos_enc,
                                                 const int* __restrict__ batch_idx,
                                                 const int* __restrict__ fi_t,
                                                 const float* __restrict__ qkw,
                                                 const float* __restrict__ qkb,
                                                 const float* __restrict__ slots,
                                                 const float* __restrict__ ipw,
                                                 const float* __restrict__ ipb,
                                                 const float* __restrict__ out_w,
                                                 const float* __restrict__ out_b,
                                                 const float* __restrict__ ln_g,
                                                 const float* __restrict__ ln_b,
                                                 float* __restrict__ aff_out,
                                                 float* __restrict__ out)
{
    __shared__ int   fi_l[S_TOT];                      // 1KB
    __shared__ float qkb_l[HEADS];
    __shared__ __align__(16) float affP[POSN][8];      // 4KB: aff then attn
    __shared__ f32x4 wfp[2][HEADS][64];                // 16KB partials
    __shared__ f32x4 wf4[HEADS][64];                   // 8KB combined
    __shared__ __align__(16) float ao_l[FEAT];         // 1KB
    __shared__ float r1[4], r2[4];

    int n = blockIdx.x, t = threadIdx.x, lane = t & 63, w = t >> 6;
    fi_l[t] = fi_t[n * S_TOT + t];
    if (t < HEADS) qkb_l[t] = qkb[n * HEADS + t];
    int b = batch_idx[n];

    const float* qk = qkw + (size_t)n * (HEADS*FEAT) + 4 * lane;
    f32x4 qw0 = *(const f32x4*)(qk + 0*FEAT);
    f32x4 qw1 = *(const f32x4*)(qk + 1*FEAT);
    f32x4 qw2 = *(const f32x4*)(qk + 2*FEAT);
    f32x4 qw3 = *(const f32x4*)(qk + 3*FEAT);
    f32x4 qw4 = *(const f32x4*)(qk + 4*FEAT);
    f32x4 qw5 = *(const f32x4*)(qk + 5*FEAT);
    f32x4 qw6 = *(const f32x4*)(qk + 6*FEAT);
    f32x4 qw7 = *(const f32x4*)(qk + 7*FEAT);
    __syncthreads();
    float qb = qkb_l[lane & 7];
    int b0 = lane & 1, b1 = (lane >> 1) & 1, b2 = (lane >> 2) & 1;

    // butterfly affinity: head h lands in lane h; writes aff (and affP if POS)
    auto dorow = [&](int s, f32x4 x, bool toLds) {
        float p0 = x[0]*qw0[0] + x[1]*qw0[1] + x[2]*qw0[2] + x[3]*qw0[3];
        float p1 = x[0]*qw1[0] + x[1]*qw1[1] + x[2]*qw1[2] + x[3]*qw1[3];
        float p2 = x[0]*qw2[0] + x[1]*qw2[1] + x[2]*qw2[2] + x[3]*qw2[3];
        float p3 = x[0]*qw3[0] + x[1]*qw3[1] + x[2]*qw3[2] + x[3]*qw3[3];
        float p4 = x[0]*qw4[0] + x[1]*qw4[1] + x[2]*qw4[2] + x[3]*qw4[3];
        float p5 = x[0]*qw5[0] + x[1]*qw5[1] + x[2]*qw5[2] + x[3]*qw5[3];
        float p6 = x[0]*qw6[0] + x[1]*qw6[1] + x[2]*qw6[2] + x[3]*qw6[3];
        float p7 = x[0]*qw7[0] + x[1]*qw7[1] + x[2]*qw7[2] + x[3]*qw7[3];
        float s0 = b0 ? p0 : p1, s1 = b0 ? p2 : p3, s2 = b0 ? p4 : p5, s3 = b0 ? p6 : p7;
        float a0 = (b0 ? p1 : p0) + __shfl_xor(s0, 1);
        float a1 = (b0 ? p3 : p2) + __shfl_xor(s1, 1);
        float a2 = (b0 ? p5 : p4) + __shfl_xor(s2, 1);
        float a3 = (b0 ? p7 : p6) + __shfl_xor(s3, 1);
        float u0 = b1 ? a0 : a1, u1 = b1 ? a2 : a3;
        float c0 = (b1 ? a1 : a0) + __shfl_xor(u0, 2);
        float c1 = (b1 ? a3 : a2) + __shfl_xor(u1, 2);
        float u2 = b2 ? c0 : c1;
        float d = (b2 ? c1 : c0) + __shfl_xor(u2, 4);
        d += __shfl_xor(d, 8);
        d += __shfl_xor(d, 16);
        d += __shfl_xor(d, 32);
        d += qb;
        if (lane < 8) {
            aff_out[(size_t)s * (NSLOT*HEADS) + n*HEADS + lane] = d;
            if (toLds) affP[s][lane] = d;
        }
    };

    auto rowaddr = [&](int s) {
        return ((size_t)fi_l[s] * BN + b) * FEAT + 4 * lane;
    };

    // ---- Phase B: POS rows p = w*32 + i, rolling depth-2, bf16 reg cache ----
    ushort4 cache[32];
    {
        f32x4 fb[2], gb[2];
        size_t a0 = rowaddr(w*32 + 0);
        fb[0] = *(const f32x4*)(features + a0); gb[0] = *(const f32x4*)(pos_enc + a0);
        size_t a1 = rowaddr(w*32 + 1);
        fb[1] = *(const f32x4*)(features + a1); gb[1] = *(const f32x4*)(pos_enc + a1);
#pragma unroll
        for (int i = 0; i < 32; i++) {
            f32x4 cf = fb[i&1], cg = gb[i&1];
            if (i + 2 < 32) {
                size_t a_ = rowaddr(w*32 + i + 2);
                fb[i&1] = *(const f32x4*)(features + a_);
                gb[i&1] = *(const f32x4*)(pos_enc + a_);
            }
            ushort4 pk;
            pk.x = bf16r(cf[0]); pk.y = bf16r(cf[1]);
            pk.z = bf16r(cf[2]); pk.w = bf16r(cf[3]);
            cache[i] = pk;
            dorow(w*32 + i, cf + cg, true);
        }
    }
    __syncthreads();

    // ---- softmax over p<128 per head (32-lane groups), in-place attn ----
    {
        int h = t >> 5, l = t & 31;
        float v0 = affP[l][h], v1 = affP[l+32][h], v2 = affP[l+64][h], v3 = affP[l+96][h];
        float m = fmaxf(fmaxf(v0, v1), fmaxf(v2, v3));
        for (int off = 16; off > 0; off >>= 1) m = fmaxf(m, __shfl_xor(m, off, 32));
        float e0 = expf(v0 - m), e1 = expf(v1 - m), e2 = expf(v2 - m), e3 = expf(v3 - m);
        float s = e0 + e1 + e2 + e3;
        for (int off = 16; off > 0; off >>= 1) s += __shfl_xor(s, off, 32);
        float inv = 1.0f / s;
        affP[l][h] = e0*inv; affP[l+32][h] = e1*inv; affP[l+64][h] = e2*inv; affP[l+96][h] = e3*inv;
    }
    __syncthreads();

    // ---- Phase C: NEG gather (rolling depth-2) interleaved with wsum -------
    f32x4 acc[8];
#pragma unroll
    for (int h = 0; h < 8; h++) acc[h] = (f32x4){0.f,0.f,0.f,0.f};
    {
        f32x4 fb[2], gb[2];
        size_t a0 = rowaddr(POSN + w*32 + 0);
        fb[0] = *(const f32x4*)(features + a0); gb[0] = *(const f32x4*)(pos_enc + a0);
        size_t a1 = rowaddr(POSN + w*32 + 1);
        fb[1] = *(const f32x4*)(features + a1); gb[1] = *(const f32x4*)(pos_enc + a1);
#pragma unroll
        for (int i = 0; i < 32; i++) {
            f32x4 cf = fb[i&1], cg = gb[i&1];
            if (i + 2 < 32) {
                size_t a_ = rowaddr(POSN + w*32 + i + 2);
                fb[i&1] = *(const f32x4*)(features + a_);
                gb[i&1] = *(const f32x4*)(pos_enc + a_);
            }
            // wsum iteration i (VALU on cached bf16 + LDS attn broadcast)
            {
                int p = w*32 + i;
                ushort4 pk = cache[i];
                f32x4 xf;
                xf[0] = bf16f(pk.x); xf[1] = bf16f(pk.y);
                xf[2] = bf16f(pk.z); xf[3] = bf16f(pk.w);
                const f32x4* ap = (const f32x4*)&affP[p][0];
                f32x4 a03 = ap[0], a47 = ap[1];
                acc[0] += xf * a03[0];
                acc[1] += xf * a03[1];
                acc[2] += xf * a03[2];
                acc[3] += xf * a03[3];
                acc[4] += xf * a47[0];
                acc[5] += xf * a47[1];
                acc[6] += xf * a47[2];
                acc[7] += xf * a47[3];
            }
            dorow(POSN + w*32 + i, cf + cg, false);
        }
    }
    // two-batch partial combine (16KB)
    if (w < 2) {
#pragma unroll
        for (int h = 0; h < 8; h++) wfp[w][h][lane] = acc[h];
    }
    __syncthreads();
    if (w >= 2) {
#pragma unroll
        for (int h = 0; h < 8; h++) {
            f32x4* dst = &wfp[w-2][h][lane];
            *dst += acc[h];
        }
    }
    __syncthreads();
    {   // combine 2 partials: 512 elements over 256 threads (2 each)
        int e0 = t, e1 = t + 256;
        int h0 = e0 >> 6, q0 = e0 & 63, h1 = e1 >> 6, q1 = e1 & 63;
        wf4[h0][q0] = wfp[0][h0][q0] + wfp[1][h0][q0];
        wf4[h1][q1] = wfp[0][h1][q1] + wfp[1][h1][q1];
    }
    __syncthreads();

    // ---- V-projection: ao[g] = vb[g] + vw[g,:]·wf[g>>5] --------------------
    {
        const float* vwrow = ipw + (size_t)(2*FEAT + t) * FEAT;
        const f32x4* wfv = &wf4[t >> 5][0];
        float s = ipb[2*FEAT + t];
#pragma unroll 8
        for (int f4i = 0; f4i < 64; f4i++) {
            f32x4 wv = *(const f32x4*)(vwrow + 4*f4i);
            f32x4 y = wfv[f4i];
            s += wv[0]*y[0] + wv[1]*y[1] + wv[2]*y[2] + wv[3]*y[3];
        }
        ao_l[t] = s;
    }
    __syncthreads();

    // ---- out-proj + residual + LN ------------------------------------------
    float xg;
    {
        const float* owrow = out_w + (size_t)t * FEAT;
        const f32x4* av = (const f32x4*)ao_l;
        float s = out_b[t] + slots[n * FEAT + t];
#pragma unroll 8
        for (int f4i = 0; f4i < 64; f4i++) {
            f32x4 wv = *(const f32x4*)(owrow + 4*f4i);
            f32x4 y = av[f4i];
            s += wv[0]*y[0] + wv[1]*y[1] + wv[2]*y[2] + wv[3]*y[3];
        }
        xg = s;
    }
    float s1 = xg, s2 = xg * xg;
    for (int off = 32; off > 0; off >>= 1) {
        s1 += __shfl_xor(s1, off);
        s2 += __shfl_xor(s2, off);
    }
    if (lane == 0) { r1[w] = s1; r2[w] = s2; }
    __syncthreads();
    {
        float sum1 = r1[0] + r1[1] + r1[2] + r1[3];
        float sum2 = r2[0] + r2[1] + r2[2] + r2[3];
        float mu  = sum1 * (1.0f / FEAT);
        float var = sum2 * (1.0f / FEAT) - mu * mu;
        float nrm = (xg - mu) * rsqrtf(var + LN_EPS);
        out[n * FEAT + t] = nrm * ln_g[t] + ln_b[t];
    }
}

extern "C" void kernel_launch(void* const* d_in, const int* in_sizes, int n_in,
                              void* d_out, int out_size, void* d_ws, size_t ws_size,
                              hipStream_t stream)
{
    (void)in_sizes; (void)n_in; (void)out_size; (void)ws_size;
    const float* slots    = (const float*)d_in[0];
    const float* features = (const float*)d_in[1];
    const float* pos_enc  = (const float*)d_in[2];
    const float* curio    = (const float*)d_in[3];
    const int*   batch_idx= (const int*)d_in[4];
    const float* ipw      = (const float*)d_in[5];
    const float* ipb      = (const float*)d_in[6];
    const float* out_w    = (const float*)d_in[7];
    const float* out_b    = (const float*)d_in[8];
    const float* ln_g     = (const float*)d_in[9];
    const float* ln_b     = (const float*)d_in[10];
    const int*   mme      = (const int*)d_in[11];
    float* out = (float*)d_out;

    char* ws = (char*)d_ws;
    int*   fi_t = (int*)ws;                                 // 512*256*4 = 512KB
    float* qkw  = (float*)(ws + (512 << 10));               // 512*2048*4 = 4MB
    float* qkb  = (float*)(ws + (512 << 10) + (4 << 20));   // 16KB
    float* aff  = out + AFF_OFF;

    hipLaunchKernelGGL(k_sample_qkw, dim3(NSLOT), dim3(256), 0, stream,
                       curio, mme, slots, ipw, ipb, fi_t, qkw, qkb);
    hipLaunchKernelGGL(k_attn, dim3(NSLOT), dim3(256), 0, stream,
                       features, pos_enc, batch_idx, fi_t, qkw, qkb, slots, ipw, ipb,
                       out_w, out_b, ln_g, ln_b, aff, out);
}

// Round 11
// 132.207 us; speedup vs baseline: 1.4742x; 1.4381x over previous
//
#include <hip/hip_runtime.h>
#include <hip/hip_bf16.h>

#define FEAT 256
#define HEADS 8
#define HD 32
#define POSN 128
#define NEGN 128
#define HWN 16384
#define BN 8
#define NSLOT 512
#define S_TOT 256
#define LN_EPS 1e-5f
#define NBKT 4096
#define AFF_OFF (NSLOT*FEAT)   /* 131072 floats: new_slots first, then affinities */

typedef float f32x4 __attribute__((ext_vector_type(4)));

__device__ __forceinline__ unsigned short bf16r(float x) {
    unsigned int u = __float_as_uint(x);
    u += 0x7FFFu + ((u >> 16) & 1u);       // round to nearest even
    return (unsigned short)(u >> 16);
}
__device__ __forceinline__ float bf16f(unsigned short h) {
    return __uint_as_float((unsigned int)h << 16);
}

// ---------------- K1: exact feat_idx sampling + folded qkw -------------------
__global__ __launch_bounds__(256) void k_sample_qkw(const float* __restrict__ curio,
                                                    const int* __restrict__ mme_p,
                                                    const float* __restrict__ slots,
                                                    const float* __restrict__ ipw,
                                                    const float* __restrict__ ipb,
                                                    int* __restrict__ fi_t,
                                                    float* __restrict__ qkw,
                                                    float* __restrict__ qkb)
{
    __shared__ unsigned int hist[NBKT];   // 16KB
    __shared__ uint16_t offs[NBKT];       // 8KB
    __shared__ uint16_t sidx[HWN];        // 32KB
    __shared__ unsigned int ssum[256];    // 1KB
    __shared__ float srow[FEAT];          // 1KB
    __shared__ float qrow[FEAT];          // 1KB
    int slot = blockIdx.x, t = threadIdx.x;
    const float* cm = curio + (size_t)slot * HWN;
    const f32x4* cm4 = (const f32x4*)cm;

    for (int i = t; i < NBKT; i += 256) hist[i] = 0;
    __syncthreads();

    // pass 1: vectorized stream + histogram; cache bucket ids in registers
    unsigned int bkA[16], bkB[16];
#pragma unroll
    for (int j = 0; j < 16; j++) {
        f32x4 v = cm4[j * 256 + t];
        int b0 = (int)(v[0] * 4096.0f); b0 = b0 < 0 ? 0 : (b0 > NBKT-1 ? NBKT-1 : b0);
        int b1 = (int)(v[1] * 4096.0f); b1 = b1 < 0 ? 0 : (b1 > NBKT-1 ? NBKT-1 : b1);
        int b2 = (int)(v[2] * 4096.0f); b2 = b2 < 0 ? 0 : (b2 > NBKT-1 ? NBKT-1 : b2);
        int b3 = (int)(v[3] * 4096.0f); b3 = b3 < 0 ? 0 : (b3 > NBKT-1 ? NBKT-1 : b3);
        bkA[j] = (unsigned int)b0 | ((unsigned int)b1 << 16);
        bkB[j] = (unsigned int)b2 | ((unsigned int)b3 << 16);
        atomicAdd(&hist[b0], 1u); atomicAdd(&hist[b1], 1u);
        atomicAdd(&hist[b2], 1u); atomicAdd(&hist[b3], 1u);
    }
    __syncthreads();

    // descending-order exclusive prefix: offs[b] = sum_{b'>b} hist[b']
    unsigned int lsum = 0;
    int base = t * 16;
    for (int j = 0; j < 16; j++) lsum += hist[NBKT-1 - (base + j)];
    ssum[t] = lsum; __syncthreads();
    for (int off = 1; off < 256; off <<= 1) {
        unsigned int v = (t >= off) ? ssum[t - off] : 0u;
        __syncthreads();
        ssum[t] += v;
        __syncthreads();
    }
    unsigned int run = ssum[t] - lsum;
    for (int j = 0; j < 16; j++) {
        int b = NBKT-1 - (base + j);
        offs[b] = (uint16_t)run;
        run += hist[b];
    }
    __syncthreads();
    for (int i = t; i < NBKT; i += 256) hist[i] = 0;
    __syncthreads();

    // pass 2: scatter from register-cached buckets (no curio re-read)
#pragma unroll
    for (int j = 0; j < 16; j++) {
        int idx0 = (j * 256 + t) * 4;
        int b0 = (int)(bkA[j] & 0xFFFFu), b1 = (int)(bkA[j] >> 16);
        int b2 = (int)(bkB[j] & 0xFFFFu), b3 = (int)(bkB[j] >> 16);
        unsigned int p0 = (unsigned int)offs[b0] + atomicAdd(&hist[b0], 1u);
        sidx[p0] = (uint16_t)(idx0 + 0);
        unsigned int p1 = (unsigned int)offs[b1] + atomicAdd(&hist[b1], 1u);
        sidx[p1] = (uint16_t)(idx0 + 1);
        unsigned int p2 = (unsigned int)offs[b2] + atomicAdd(&hist[b2], 1u);
        sidx[p2] = (uint16_t)(idx0 + 2);
        unsigned int p3 = (unsigned int)offs[b3] + atomicAdd(&hist[b3], 1u);
        sidx[p3] = (uint16_t)(idx0 + 3);
    }
    __syncthreads();

    // exact rank selection (argsort of -v, stable: value desc, idx asc)
    int mme = mme_p[0];
    int stride = (HWN - POSN - mme) / NEGN;          // 127 for mme=0
    int r = (t < POSN) ? t : (POSN + stride * (t - POSN));
    int lo = 0, hi = NBKT - 1;
    while (lo < hi) { int mid = (lo + hi) >> 1; if ((int)offs[mid] <= r) hi = mid; else lo = mid + 1; }
    int bkt = lo;
    int start = (int)offs[bkt];
    int cnt   = (int)hist[bkt];
    int rr = r - start;
    int besti = sidx[start + (rr < cnt ? rr : 0)];
    for (int j = 0; j < cnt; j++) {
        int ij = sidx[start + j];
        float vj = cm[ij];
        int rank = 0;
        for (int j2 = 0; j2 < cnt; j2++) {
            int i2 = sidx[start + j2];
            float v2 = cm[i2];
            if (v2 > vj || (v2 == vj && i2 < ij)) rank++;
        }
        if (rank == rr) { besti = ij; break; }
    }
    fi_t[slot * S_TOT + t] = besti;   // fi_t[n][s]

    // ---- folded qkw for this slot ----
    __syncthreads();
    srow[t] = slots[slot * FEAT + t];
    __syncthreads();
    {
        const float* qwrow = ipw + (size_t)t * FEAT;
        float acc = 0.f;
#pragma unroll 8
        for (int f = 0; f < FEAT; f++) acc += srow[f] * qwrow[f];
        const float scaling = 0.17677669529663687f;     // 32^-0.5
        qrow[t] = (acc + ipb[t]) * scaling;
    }
    __syncthreads();
    if (t < HEADS) {
        float s = 0.f;
        for (int d = 0; d < HD; d++) s += qrow[t*HD + d] * ipb[FEAT + t*HD + d];
        qkb[slot * HEADS + t] = s;
    }
    const float* kw = ipw + FEAT * FEAT;
    for (int e = t; e < HEADS * FEAT; e += 256) {
        int h = e >> 8, f = e & 255;
        float s = 0.f;
#pragma unroll
        for (int d = 0; d < HD; d++) s += qrow[h*HD + d] * kw[(h*HD + d) * FEAT + f];
        qkw[(size_t)slot * (HEADS*FEAT) + e] = s;
    }
}

// ---------------- K2: fused attention (R4 structure + NEG/wsum interleave) ---
// One block per slot, 512 threads (8 waves). Phase B: POS gather (rows w+8i,
// depth-2 prefetch), bf16-packed register cache + affinities. Softmax. Phase
// C: NEG gather (depth-2) with ONE weighted-sum step interleaved into each
// iteration, hiding wsum VALU under the NEG HBM stream. Then R4's epilogue.
__global__ __launch_bounds__(512) void k_attn(const float* __restrict__ features,
                                              const float* __restrict__ pos_enc,
                                              const int* __restrict__ batch_idx,
                                              const int* __restrict__ fi_t,
                                              const float* __restrict__ qkw,
                                              const float* __restrict__ qkb,
                                              const float* __restrict__ slots,
                                              const float* __restrict__ ipw,
                                              const float* __restrict__ ipb,
                                              const float* __restrict__ out_w,
                                              const float* __restrict__ out_b,
                                              const float* __restrict__ ln_g,
                                              const float* __restrict__ ln_b,
                                              float* __restrict__ aff_out,
                                              float* __restrict__ out)
{
    __shared__ int   fi_l[S_TOT];                      // 1KB
    __shared__ float qkb_l[HEADS];
    __shared__ __align__(16) float affP[POSN][8];      // 4KB: aff then attn
    __shared__ f32x4 wfp[4][HEADS][64];                // 32KB per-wave partials
    __shared__ f32x4 wf4[HEADS][64];                   // 8KB combined
    __shared__ float aoh[512];                         // 2KB
    __shared__ __align__(16) float ao_l[FEAT];         // 1KB
    __shared__ float xgh[512];                         // 2KB
    __shared__ float r1[4], r2[4];

    int n = blockIdx.x, t = threadIdx.x, lane = t & 63, w = t >> 6;
    if (t < S_TOT) fi_l[t] = fi_t[n * S_TOT + t];
    if (t < HEADS) qkb_l[t] = qkb[n * HEADS + t];
    int b = batch_idx[n];

    const float* qk = qkw + (size_t)n * (HEADS*FEAT) + 4 * lane;
    f32x4 qw0 = *(const f32x4*)(qk + 0*FEAT);
    f32x4 qw1 = *(const f32x4*)(qk + 1*FEAT);
    f32x4 qw2 = *(const f32x4*)(qk + 2*FEAT);
    f32x4 qw3 = *(const f32x4*)(qk + 3*FEAT);
    f32x4 qw4 = *(const f32x4*)(qk + 4*FEAT);
    f32x4 qw5 = *(const f32x4*)(qk + 5*FEAT);
    f32x4 qw6 = *(const f32x4*)(qk + 6*FEAT);
    f32x4 qw7 = *(const f32x4*)(qk + 7*FEAT);
    __syncthreads();
    float qb = qkb_l[lane & 7];
    int b0 = lane & 1, b1 = (lane >> 1) & 1, b2 = (lane >> 2) & 1;

    auto dorow = [&](int p, f32x4 x, bool toLds) {
        float p0 = x[0]*qw0[0] + x[1]*qw0[1] + x[2]*qw0[2] + x[3]*qw0[3];
        float p1 = x[0]*qw1[0] + x[1]*qw1[1] + x[2]*qw1[2] + x[3]*qw1[3];
        float p2 = x[0]*qw2[0] + x[1]*qw2[1] + x[2]*qw2[2] + x[3]*qw2[3];
        float p3 = x[0]*qw3[0] + x[1]*qw3[1] + x[2]*qw3[2] + x[3]*qw3[3];
        float p4 = x[0]*qw4[0] + x[1]*qw4[1] + x[2]*qw4[2] + x[3]*qw4[3];
        float p5 = x[0]*qw5[0] + x[1]*qw5[1] + x[2]*qw5[2] + x[3]*qw5[3];
        float p6 = x[0]*qw6[0] + x[1]*qw6[1] + x[2]*qw6[2] + x[3]*qw6[3];
        float p7 = x[0]*qw7[0] + x[1]*qw7[1] + x[2]*qw7[2] + x[3]*qw7[3];
        float s0 = b0 ? p0 : p1, s1 = b0 ? p2 : p3, s2 = b0 ? p4 : p5, s3 = b0 ? p6 : p7;
        float a0 = (b0 ? p1 : p0) + __shfl_xor(s0, 1);
        float a1 = (b0 ? p3 : p2) + __shfl_xor(s1, 1);
        float a2 = (b0 ? p5 : p4) + __shfl_xor(s2, 1);
        float a3 = (b0 ? p7 : p6) + __shfl_xor(s3, 1);
        float u0 = b1 ? a0 : a1, u1 = b1 ? a2 : a3;
        float c0 = (b1 ? a1 : a0) + __shfl_xor(u0, 2);
        float c1 = (b1 ? a3 : a2) + __shfl_xor(u1, 2);
        float u2 = b2 ? c0 : c1;
        float d = (b2 ? c1 : c0) + __shfl_xor(u2, 4);
        d += __shfl_xor(d, 8);
        d += __shfl_xor(d, 16);
        d += __shfl_xor(d, 32);
        d += qb;
        if (lane < 8) {
            aff_out[(size_t)p * (NSLOT*HEADS) + n*HEADS + lane] = d;
            if (toLds) affP[p][lane] = d;
        }
    };

    auto rowaddr = [&](int s) {
        return ((size_t)fi_l[s] * BN + b) * FEAT + 4 * lane;
    };

    // ---- Phase B: POS rows p = w + 8i, bf16 cache, depth-2 prefetch ----
    ushort4 cache[16];
    {
        size_t aA = rowaddr(w);
        size_t aB = rowaddr(w + 8);
        f32x4 fA = *(const f32x4*)(features + aA), gA = *(const f32x4*)(pos_enc + aA);
        f32x4 fB = *(const f32x4*)(features + aB), gB = *(const f32x4*)(pos_enc + aB);
#pragma unroll
        for (int i = 0; i < 16; i += 2) {
            f32x4 cf = fA, cg = gA;
            if (i + 2 < 16) {
                size_t nb = rowaddr(w + 8*(i+2));
                fA = *(const f32x4*)(features + nb); gA = *(const f32x4*)(pos_enc + nb);
            }
            { ushort4 pk; pk.x = bf16r(cf[0]); pk.y = bf16r(cf[1]);
              pk.z = bf16r(cf[2]); pk.w = bf16r(cf[3]); cache[i] = pk; }
            dorow(w + 8*i, cf + cg, true);
            f32x4 cf2 = fB, cg2 = gB;
            if (i + 3 < 16) {
                size_t nb = rowaddr(w + 8*(i+3));
                fB = *(const f32x4*)(features + nb); gB = *(const f32x4*)(pos_enc + nb);
            }
            { ushort4 pk; pk.x = bf16r(cf2[0]); pk.y = bf16r(cf2[1]);
              pk.z = bf16r(cf2[2]); pk.w = bf16r(cf2[3]); cache[i+1] = pk; }
            dorow(w + 8*(i+1), cf2 + cg2, true);
        }
    }
    __syncthreads();

    // ---- softmax over p<128 per head (t<256: 32-lane groups), in-place ----
    if (t < 256) {
        int h = t >> 5, l = t & 31;
        float v0 = affP[l][h], v1 = affP[l+32][h], v2 = affP[l+64][h], v3 = affP[l+96][h];
        float m = fmaxf(fmaxf(v0, v1), fmaxf(v2, v3));
        for (int off = 16; off > 0; off >>= 1) m = fmaxf(m, __shfl_xor(m, off, 32));
        float e0 = expf(v0 - m), e1 = expf(v1 - m), e2 = expf(v2 - m), e3 = expf(v3 - m);
        float s = e0 + e1 + e2 + e3;
        for (int off = 16; off > 0; off >>= 1) s += __shfl_xor(s, off, 32);
        float inv = 1.0f / s;
        affP[l][h] = e0*inv; affP[l+32][h] = e1*inv; affP[l+64][h] = e2*inv; affP[l+96][h] = e3*inv;
    }
    __syncthreads();

    // ---- Phase C: NEG gather (depth-2) interleaved with weighted sum -------
    f32x4 acc[8];
#pragma unroll
    for (int h = 0; h < 8; h++) acc[h] = (f32x4){0.f,0.f,0.f,0.f};
    {
        auto wstep = [&](int i) {
            int p = w + 8*i;
            ushort4 pk = cache[i];
            f32x4 xf;
            xf[0] = bf16f(pk.x); xf[1] = bf16f(pk.y);
            xf[2] = bf16f(pk.z); xf[3] = bf16f(pk.w);
            const f32x4* ap = (const f32x4*)&affP[p][0];
            f32x4 a03 = ap[0], a47 = ap[1];
            acc[0] += xf * a03[0];
            acc[1] += xf * a03[1];
            acc[2] += xf * a03[2];
            acc[3] += xf * a03[3];
            acc[4] += xf * a47[0];
            acc[5] += xf * a47[1];
            acc[6] += xf * a47[2];
            acc[7] += xf * a47[3];
        };
        size_t aA = rowaddr(POSN + w);
        size_t aB = rowaddr(POSN + w + 8);
        f32x4 fA = *(const f32x4*)(features + aA), gA = *(const f32x4*)(pos_enc + aA);
        f32x4 fB = *(const f32x4*)(features + aB), gB = *(const f32x4*)(pos_enc + aB);
#pragma unroll
        for (int i = 0; i < 16; i += 2) {
            f32x4 cf = fA, cg = gA;
            if (i + 2 < 16) {
                size_t nb = rowaddr(POSN + w + 8*(i+2));
                fA = *(const f32x4*)(features + nb); gA = *(const f32x4*)(pos_enc + nb);
            }
            wstep(i);
            dorow(POSN + w + 8*i, cf + cg, false);
            f32x4 cf2 = fB, cg2 = gB;
            if (i + 3 < 16) {
                size_t nb = rowaddr(POSN + w + 8*(i+3));
                fB = *(const f32x4*)(features + nb); gB = *(const f32x4*)(pos_enc + nb);
            }
            wstep(i+1);
            dorow(POSN + w + 8*(i+1), cf2 + cg2, false);
        }
    }
    // two-batch combine into 32KB of partials
    if (w < 4) {
#pragma unroll
        for (int h = 0; h < 8; h++) wfp[w][h][lane] = acc[h];
    }
    __syncthreads();
    if (w >= 4) {
#pragma unroll
        for (int h = 0; h < 8; h++) wfp[w-4][h][lane] += acc[h];
    }
    __syncthreads();
    {   // combine 4 partials (HEADS*64 = 512 elements, one per thread)
        int h = t >> 6, q2 = t & 63;
        f32x4 s = wfp[0][h][q2] + wfp[1][h][q2] + wfp[2][h][q2] + wfp[3][h][q2];
        wf4[h][q2] = s;
    }
    __syncthreads();

    // V-projection split in half across 512 threads
    {
        int g = t & 255, half = t >> 8;
        const float* vwrow = ipw + (size_t)(2*FEAT + g) * FEAT + half*128;
        const f32x4* wfv = &wf4[g >> 5][half*32];
        float s = 0.f;
#pragma unroll 8
        for (int f4i = 0; f4i < 32; f4i++) {
            f32x4 wv = *(const f32x4*)(vwrow + 4*f4i);
            f32x4 y = wfv[f4i];
            s += wv[0]*y[0] + wv[1]*y[1] + wv[2]*y[2] + wv[3]*y[3];
        }
        aoh[t] = s;
    }
    __syncthreads();
    if (t < 256) ao_l[t] = aoh[t] + aoh[t + 256] + ipb[2*FEAT + t];
    __syncthreads();

    // out-projection split in half
    {
        int g = t & 255, half = t >> 8;
        const float* owrow = out_w + (size_t)g * FEAT + half*128;
        const f32x4* av = (const f32x4*)&ao_l[half*128];
        float s = 0.f;
#pragma unroll 8
        for (int f4i = 0; f4i < 32; f4i++) {
            f32x4 wv = *(const f32x4*)(owrow + 4*f4i);
            f32x4 y = av[f4i];
            s += wv[0]*y[0] + wv[1]*y[1] + wv[2]*y[2] + wv[3]*y[3];
        }
        xgh[t] = s;
    }
    __syncthreads();

    float xg = 0.f;
    if (t < 256) {
        xg = xgh[t] + xgh[t + 256] + out_b[t] + slots[n * FEAT + t];
        float s1 = xg, s2 = xg * xg;
        for (int off = 32; off > 0; off >>= 1) {
            s1 += __shfl_xor(s1, off);
            s2 += __shfl_xor(s2, off);
        }
        if ((t & 63) == 0) { r1[t >> 6] = s1; r2[t >> 6] = s2; }
    }
    __syncthreads();
    if (t < 256) {
        float sum1 = r1[0] + r1[1] + r1[2] + r1[3];
        float sum2 = r2[0] + r2[1] + r2[2] + r2[3];
        float mu  = sum1 * (1.0f / FEAT);
        float var = sum2 * (1.0f / FEAT) - mu * mu;
        float nrm = (xg - mu) * rsqrtf(var + LN_EPS);
        out[n * FEAT + t] = nrm * ln_g[t] + ln_b[t];
    }
}

extern "C" void kernel_launch(void* const* d_in, const int* in_sizes, int n_in,
                              void* d_out, int out_size, void* d_ws, size_t ws_size,
                              hipStream_t stream)
{
    (void)in_sizes; (void)n_in; (void)out_size; (void)ws_size;
    const float* slots    = (const float*)d_in[0];
    const float* features = (const float*)d_in[1];
    const float* pos_enc  = (const float*)d_in[2];
    const float* curio    = (const float*)d_in[3];
    const int*   batch_idx= (const int*)d_in[4];
    const float* ipw      = (const float*)d_in[5];
    const float* ipb      = (const float*)d_in[6];
    const float* out_w    = (const float*)d_in[7];
    const float* out_b    = (const float*)d_in[8];
    const float* ln_g     = (const float*)d_in[9];
    const float* ln_b     = (const float*)d_in[10];
    const int*   mme      = (const int*)d_in[11];
    float* out = (float*)d_out;

    char* ws = (char*)d_ws;
    int*   fi_t = (int*)ws;                                 // 512*256*4 = 512KB
    float* qkw  = (float*)(ws + (512 << 10));               // 512*2048*4 = 4MB
    float* qkb  = (float*)(ws + (512 << 10) + (4 << 20));   // 16KB
    float* aff  = out + AFF_OFF;

    hipLaunchKernelGGL(k_sample_qkw, dim3(NSLOT), dim3(256), 0, stream,
                       curio, mme, slots, ipw, ipb, fi_t, qkw, qkb);
    hipLaunchKernelGGL(k_attn, dim3(NSLOT), dim3(512), 0, stream,
                       features, pos_enc, batch_idx, fi_t, qkw, qkb, slots, ipw, ipb,
                       out_w, out_b, ln_g, ln_b, aff, out);
}